// Round 4
// baseline (372.044 us; speedup 1.0000x reference)
//
#include <hip/hip_runtime.h>

// QPChargeNormalization: per batch row b (n = 8192 = 4096 iso + 4096 aniso):
//   h = u/2 = (sum(charge[b]) - q.c) / (q.q);  x = c + h*q
//
// R1/R3 lesson: block-wide payload-in-registers across __syncthreads loses —
// the RA spills (VGPR=40, scratch round-trip) and the barrier's vmcnt(0)
// drain serializes load/store phases (2.1-2.4 TB/s).
//
// This version is BARRIER-FREE: one wave per row (4 independent waves per
// 256-thread block, no __syncthreads, no LDS). Pass 1 streams q,c for the
// dot products (no payload held), wave-64 shuffle reduce -> h. Pass 2
// re-reads q,c (LLC-hit: chip-resident working set ~128 MB < 256 MB LLC)
// and writes x with nontemporal vec4 stores. Waves are fully independent ->
// loads/stores overlap chip-wide like a pure streaming kernel.

#define HALF_N 4096   // elements per row in each of the iso/aniso halves
#define BLOCK  256
#define WPB    4      // waves (rows) per block

typedef float v4f __attribute__((ext_vector_type(4)));

__global__ __launch_bounds__(BLOCK, 4) void qp_charge_norm_kernel(
    const float* __restrict__ c_iso,
    const float* __restrict__ c_aniso,
    const float* __restrict__ q_iso,
    const float* __restrict__ q_aniso,
    const float* __restrict__ charge,   // [B, 256]
    float* __restrict__ out,            // [B*4096 iso][B*4096 aniso]
    int B)
{
    const int tid  = threadIdx.x;
    const int lane = tid & 63;
    const int wave = tid >> 6;
    const int b    = blockIdx.x * WPB + wave;   // one row per wave

    const v4f* ci = (const v4f*)(c_iso   + (size_t)b * HALF_N);
    const v4f* ca = (const v4f*)(c_aniso + (size_t)b * HALF_N);
    const v4f* qi = (const v4f*)(q_iso   + (size_t)b * HALF_N);
    const v4f* qa = (const v4f*)(q_aniso + (size_t)b * HALF_N);

    // ---- Pass 1: stream q,c -> per-lane partial dots (nothing held) ----
    // Row half = 1024 v4f; per lane 16 (index j*64 + lane, coalesced 16B).
    float qc = 0.0f, qq = 0.0f;
#pragma unroll
    for (int j = 0; j < 16; ++j) {
        const int idx = j * 64 + lane;
        v4f cvi = ci[idx], qvi = qi[idx];
        v4f cva = ca[idx], qva = qa[idx];
        qc += qvi.x * cvi.x + qvi.y * cvi.y + qvi.z * cvi.z + qvi.w * cvi.w;
        qq += qvi.x * qvi.x + qvi.y * qvi.y + qvi.z * qvi.z + qvi.w * qvi.w;
        qc += qva.x * cva.x + qva.y * cva.y + qva.z * cva.z + qva.w * cva.w;
        qq += qva.x * qva.x + qva.y * qva.y + qva.z * qva.z + qva.w * qva.w;
    }
    // charge row: 256 floats = 64 v4f, one per lane.
    v4f chv = ((const v4f*)(charge + (size_t)b * 256))[lane];
    float Qp = chv.x + chv.y + chv.z + chv.w;

    // ---- Wave-64 shuffle reduce (no LDS, no barrier) ----
#pragma unroll
    for (int off = 32; off > 0; off >>= 1) {
        qc += __shfl_down(qc, off, 64);
        qq += __shfl_down(qq, off, 64);
        Qp += __shfl_down(Qp, off, 64);
    }
    // broadcast lane 0's result to all lanes
    const float h = __shfl((Qp - qc) / qq, 0, 64);   // u/2

    // ---- Pass 2: re-read q,c (LLC-backed) and store x ----
    v4f* oi = (v4f*)(out + (size_t)b * HALF_N);
    v4f* oa = (v4f*)(out + (size_t)B * HALF_N + (size_t)b * HALF_N);
#pragma unroll
    for (int j = 0; j < 16; ++j) {
        const int idx = j * 64 + lane;
        v4f r = ci[idx] + h * qi[idx];
        __builtin_nontemporal_store(r, &oi[idx]);
        v4f s = ca[idx] + h * qa[idx];
        __builtin_nontemporal_store(s, &oa[idx]);
    }
}

extern "C" void kernel_launch(void* const* d_in, const int* in_sizes, int n_in,
                              void* d_out, int out_size, void* d_ws, size_t ws_size,
                              hipStream_t stream) {
    const float* c_iso   = (const float*)d_in[0];
    const float* c_aniso = (const float*)d_in[1];
    const float* q_iso   = (const float*)d_in[2];
    const float* q_aniso = (const float*)d_in[3];
    const float* charge  = (const float*)d_in[4];
    float* out = (float*)d_out;

    const int B = in_sizes[0] / HALF_N;   // 4096

    qp_charge_norm_kernel<<<B / WPB, BLOCK, 0, stream>>>(
        c_iso, c_aniso, q_iso, q_aniso, charge, out, B);
}

// Round 5
// 329.452 us; speedup vs baseline: 1.1293x; 1.1293x over previous
//
#include <hip/hip_runtime.h>

// QPChargeNormalization: per row b (n = 8192 = 4096 iso + 4096 aniso):
//   h = u/2 = (sum(charge[b]) - q.c) / (q.q);  x = c + h*q
//
// R1-R4 lessons: every structure with VGPR-destination loads + a reduce join
// point plateaus at 2.1-2.7 TB/s (outstanding-load cap ~8/wave, vmcnt(0)
// drains); LLC-residency bets fail at chip scale (R4: +146 MB HBM re-reads).
//
// This version: global_load_lds DMA staging. One 512-thread block per row;
// the row's c,q (64 KB) is DMA'd to LDS with no VGPR destinations (all 64
// 1-KB chunks in flight), then dots AND epilogue read LDS only -> zero
// global re-reads, compulsory traffic 388 MB -> ~62 us roofline.
// 2 blocks/CU (LDS-bound): one block's DMA drain overlaps the other's crunch.

#define HALF_N 4096          // floats per row half (iso or aniso)
#define BLOCK  512
#define NWAVE  (BLOCK / 64)  // 8 waves

typedef float v4f __attribute__((ext_vector_type(4)));

// Async global->LDS, 16 B per lane. LDS dest: wave-uniform base + lane*16.
__device__ __forceinline__ void dma16(const float* g, float* l) {
    __builtin_amdgcn_global_load_lds(
        (const __attribute__((address_space(1))) float*)g,
        (__attribute__((address_space(3))) float*)l,
        16, 0, 0);
}

__global__ __launch_bounds__(BLOCK, 4) void qp_charge_norm_kernel(
    const float* __restrict__ c_iso,
    const float* __restrict__ c_aniso,
    const float* __restrict__ q_iso,
    const float* __restrict__ q_aniso,
    const float* __restrict__ charge,   // [B, 256]
    float* __restrict__ out,            // [B*4096 iso][B*4096 aniso]
    int B)
{
    __shared__ float sc[2 * HALF_N];    // [iso 4096 | aniso 4096]
    __shared__ float sq[2 * HALF_N];
    __shared__ float s_qc[NWAVE], s_qq[NWAVE], s_Q[NWAVE];

    const int tid  = threadIdx.x;
    const int lane = tid & 63;
    const int wave = tid >> 6;
    const int b    = blockIdx.x;

    const float* ci = c_iso   + (size_t)b * HALF_N;
    const float* ca = c_aniso + (size_t)b * HALF_N;
    const float* qi = q_iso   + (size_t)b * HALF_N;
    const float* qa = q_aniso + (size_t)b * HALF_N;

    // ---- Phase 1: DMA the whole row into LDS (no VGPR destinations) ----
    // Each half = 4096 floats = 16 chunks of 256 floats (1 KB = 64 lanes x 16B).
    // Wave w owns chunks {2w, 2w+1} of each of the 4 arrays -> 8 DMAs/wave.
#pragma unroll
    for (int t = 0; t < 2; ++t) {
        const int k   = wave * 2 + t;       // chunk index 0..15
        const int off = k * 256;            // float offset of chunk
        const int gl  = off + lane * 4;     // per-lane source float offset
        dma16(ci + gl, sc + off);                    // iso c
        dma16(ca + gl, sc + HALF_N + off);           // aniso c
        dma16(qi + gl, sq + off);                    // iso q
        dma16(qa + gl, sq + HALF_N + off);           // aniso q
    }
    // charge row: 256 floats; threads 0..255 take one each
    float Qp = (tid < 256) ? charge[(size_t)b * 256 + tid] : 0.0f;

    __syncthreads();   // compiler emits s_waitcnt vmcnt(0) -> DMA complete

    // ---- Phase 2: dots from LDS ----
    // 2048 v4f of c and q; 512 threads -> 4 v4f each per array.
    const v4f* sc4 = (const v4f*)sc;
    const v4f* sq4 = (const v4f*)sq;
    float qc = 0.0f, qq = 0.0f;
#pragma unroll
    for (int j = 0; j < 4; ++j) {
        const int idx = j * BLOCK + tid;    // contiguous per wave -> conflict-free
        v4f cv = sc4[idx];
        v4f qv = sq4[idx];
        qc += qv.x * cv.x + qv.y * cv.y + qv.z * cv.z + qv.w * cv.w;
        qq += qv.x * qv.x + qv.y * qv.y + qv.z * qv.z + qv.w * qv.w;
    }
#pragma unroll
    for (int off = 32; off > 0; off >>= 1) {
        qc += __shfl_down(qc, off, 64);
        qq += __shfl_down(qq, off, 64);
        Qp += __shfl_down(Qp, off, 64);
    }
    if (lane == 0) { s_qc[wave] = qc; s_qq[wave] = qq; s_Q[wave] = Qp; }
    __syncthreads();

    float tqc = 0.0f, tqq = 0.0f, tQ = 0.0f;
#pragma unroll
    for (int w = 0; w < NWAVE; ++w) { tqc += s_qc[w]; tqq += s_qq[w]; tQ += s_Q[w]; }
    const float h = (tQ - tqc) / tqq;   // u/2, redundant per thread (broadcast reads)

    // ---- Phase 3: epilogue from LDS, nontemporal stores ----
    v4f* oi = (v4f*)(out + (size_t)b * HALF_N);
    v4f* oa = (v4f*)(out + (size_t)B * HALF_N + (size_t)b * HALF_N);
#pragma unroll
    for (int j = 0; j < 2; ++j) {
        const int idx = j * BLOCK + tid;          // v4f index within iso half
        v4f r = sc4[idx] + h * sq4[idx];
        __builtin_nontemporal_store(r, &oi[idx]);
        const int idxA = idx + HALF_N / 4;        // aniso half in LDS
        v4f s = sc4[idxA] + h * sq4[idxA];
        __builtin_nontemporal_store(s, &oa[idx]);
    }
}

extern "C" void kernel_launch(void* const* d_in, const int* in_sizes, int n_in,
                              void* d_out, int out_size, void* d_ws, size_t ws_size,
                              hipStream_t stream) {
    const float* c_iso   = (const float*)d_in[0];
    const float* c_aniso = (const float*)d_in[1];
    const float* q_iso   = (const float*)d_in[2];
    const float* q_aniso = (const float*)d_in[3];
    const float* charge  = (const float*)d_in[4];
    float* out = (float*)d_out;

    const int B = in_sizes[0] / HALF_N;   // 4096

    qp_charge_norm_kernel<<<B, BLOCK, 0, stream>>>(
        c_iso, c_aniso, q_iso, q_aniso, charge, out, B);
}